// Round 2
// baseline (1217.894 us; speedup 1.0000x reference)
//
#include <hip/hip_runtime.h>
#include <hip/hip_bf16.h>

// MultiHeadAttention: x[2,2048,1024] fp32; w*[1024,1024] (in,out); b* zeros.
// SCALE = 1/head_dim = 1/64. Mask keeps j >= i (anti-causal upper triangle).
// Round 2: fix flash tile loader (was loading only 16/64 rows). fp32 baseline.

constexpr int NH    = 16;
constexpr int HD    = 64;
constexpr int BATCH = 2;
constexpr int SEQ   = 2048;
constexpr int DIMSZ = 1024;
constexpr int MTOT  = BATCH * SEQ;          // 4096
constexpr float SCALE = 1.0f / 64.0f;

// ---------------------------------------------------------------------------
// GEMM: C = A[M,K] @ W[K,N] + bias[N].  BM=BN=64, BK=16, 256 thr, 4x4/thread.
// MODE 0: scatter output into [B,H,S,hd] (n0 tile == one head, since BN==hd).
// MODE 1: plain row-major [M,N] output.
// ---------------------------------------------------------------------------
template <int MODE>
__global__ __launch_bounds__(256, 2) void gemm_bias_kernel(
    const float* __restrict__ A, const float* __restrict__ W,
    const float* __restrict__ bias, float* __restrict__ C, int K, int N)
{
    __shared__ float As[64][20];  // [m][kk]
    __shared__ float Bs[16][68];  // [kk][n]

    const int tid = threadIdx.x;
    const int tx = tid & 15, ty = tid >> 4;
    const int n0 = blockIdx.x * 64;
    const int m0 = blockIdx.y * 64;

    const int ar = tid >> 2, ak = (tid & 3) * 4;   // A loader: 64x16 tile
    const int br = tid >> 4, bn = (tid & 15) * 4;  // W loader: 16x64 tile

    float acc[4][4] = {};

    for (int k0 = 0; k0 < K; k0 += 16) {
        const float4 a4 = *reinterpret_cast<const float4*>(&A[(size_t)(m0 + ar) * K + k0 + ak]);
        const float4 b4 = *reinterpret_cast<const float4*>(&W[(size_t)(k0 + br) * N + n0 + bn]);
        *reinterpret_cast<float4*>(&As[ar][ak]) = a4;
        *reinterpret_cast<float4*>(&Bs[br][bn]) = b4;
        __syncthreads();
#pragma unroll
        for (int kk = 0; kk < 16; kk += 4) {
            float4 a[4], b[4];
#pragma unroll
            for (int i = 0; i < 4; ++i)
                a[i] = *reinterpret_cast<const float4*>(&As[ty * 4 + i][kk]);
#pragma unroll
            for (int u = 0; u < 4; ++u)
                b[u] = *reinterpret_cast<const float4*>(&Bs[kk + u][tx * 4]);
#pragma unroll
            for (int u = 0; u < 4; ++u) {
#pragma unroll
                for (int i = 0; i < 4; ++i) {
                    const float av = reinterpret_cast<const float*>(&a[i])[u];
                    acc[i][0] = fmaf(av, b[u].x, acc[i][0]);
                    acc[i][1] = fmaf(av, b[u].y, acc[i][1]);
                    acc[i][2] = fmaf(av, b[u].z, acc[i][2]);
                    acc[i][3] = fmaf(av, b[u].w, acc[i][3]);
                }
            }
        }
        __syncthreads();
    }

    const float4 bv = *reinterpret_cast<const float4*>(&bias[n0 + tx * 4]);
#pragma unroll
    for (int i = 0; i < 4; ++i) {
        float4 o;
        o.x = acc[i][0] + bv.x;
        o.y = acc[i][1] + bv.y;
        o.z = acc[i][2] + bv.z;
        o.w = acc[i][3] + bv.w;
        const int m = m0 + ty * 4 + i;
        if (MODE == 0) {
            const int b = m >> 11;              // m / SEQ
            const int s = m & (SEQ - 1);
            const int h = blockIdx.x;
            float* dst = &C[((size_t)(b * NH + h) * SEQ + s) * HD + tx * 4];
            *reinterpret_cast<float4*>(dst) = o;
        } else {
            *reinterpret_cast<float4*>(&C[(size_t)m * N + n0 + tx * 4]) = o;
        }
    }
}

// ---------------------------------------------------------------------------
// Flash attention, fp32. One block = 64 query rows of one (b,h).
// Mask keeps j >= i, so iterate j-tiles from the diagonal tile upward.
// ---------------------------------------------------------------------------
__global__ __launch_bounds__(256, 2) void flash_attn_kernel(
    const float* __restrict__ q, const float* __restrict__ k,
    const float* __restrict__ v, float* __restrict__ o)
{
    __shared__ float Qs[64][68];   // [i][d] (pre-scaled by SCALE)
    __shared__ float Kts[64][68];  // [d][c]  (K transposed)
    __shared__ float Vs[64][68];   // [c][d]
    __shared__ float Ps[64][68];   // [i][c]

    const int tid = threadIdx.x;
    const int tx = tid & 15, ty = tid >> 4;
    const int qt = blockIdx.x;          // 0..31
    const int h = blockIdx.y, b = blockIdx.z;
    const size_t head_off = (size_t)(b * NH + h) * SEQ * HD;
    const float* qh = q + head_off;
    const float* kh = k + head_off;
    const float* vh = v + head_off;

    const int i0 = qt * 64;
    const int lr = tid >> 4, lc = (tid & 15) * 4;   // 16 rows/pass, 4 passes

#pragma unroll
    for (int rr = 0; rr < 64; rr += 16) {
        float4 q4 = *reinterpret_cast<const float4*>(&qh[(size_t)(i0 + rr + lr) * HD + lc]);
        q4.x *= SCALE; q4.y *= SCALE; q4.z *= SCALE; q4.w *= SCALE;
        *reinterpret_cast<float4*>(&Qs[rr + lr][lc]) = q4;
    }

    float m_run[4], l_run[4], O[4][4];
#pragma unroll
    for (int i = 0; i < 4; ++i) {
        m_run[i] = -1e30f;
        l_run[i] = 0.f;
        O[i][0] = O[i][1] = O[i][2] = O[i][3] = 0.f;
    }

    for (int jt = qt; jt < SEQ / 64; ++jt) {
        __syncthreads();   // previous PV (reads Ps,Vs) done before overwrite
        {
            const int j0 = jt * 64;
#pragma unroll
            for (int rr = 0; rr < 64; rr += 16) {
                const float4 k4 = *reinterpret_cast<const float4*>(&kh[(size_t)(j0 + rr + lr) * HD + lc]);
                Kts[lc + 0][rr + lr] = k4.x;
                Kts[lc + 1][rr + lr] = k4.y;
                Kts[lc + 2][rr + lr] = k4.z;
                Kts[lc + 3][rr + lr] = k4.w;
                const float4 v4 = *reinterpret_cast<const float4*>(&vh[(size_t)(j0 + rr + lr) * HD + lc]);
                *reinterpret_cast<float4*>(&Vs[rr + lr][lc]) = v4;
            }
        }
        __syncthreads();

        // ---- S = (Q*SCALE) @ K^T -------------------------------------------
        float s[4][4] = {};
#pragma unroll
        for (int d0 = 0; d0 < HD; d0 += 4) {
            float4 aq[4], bk[4];
#pragma unroll
            for (int i = 0; i < 4; ++i)
                aq[i] = *reinterpret_cast<const float4*>(&Qs[ty * 4 + i][d0]);
#pragma unroll
            for (int u = 0; u < 4; ++u)
                bk[u] = *reinterpret_cast<const float4*>(&Kts[d0 + u][tx * 4]);
#pragma unroll
            for (int u = 0; u < 4; ++u) {
#pragma unroll
                for (int i = 0; i < 4; ++i) {
                    const float av = reinterpret_cast<const float*>(&aq[i])[u];
                    s[i][0] = fmaf(av, bk[u].x, s[i][0]);
                    s[i][1] = fmaf(av, bk[u].y, s[i][1]);
                    s[i][2] = fmaf(av, bk[u].z, s[i][2]);
                    s[i][3] = fmaf(av, bk[u].w, s[i][3]);
                }
            }
        }

        // ---- mask (diagonal tile only; j >= i is allowed) -------------------
        if (jt == qt) {
#pragma unroll
            for (int i = 0; i < 4; ++i)
#pragma unroll
                for (int j = 0; j < 4; ++j)
                    if (tx * 4 + j < ty * 4 + i) s[i][j] = -1e30f;
        }

        // ---- online softmax -------------------------------------------------
#pragma unroll
        for (int i = 0; i < 4; ++i) {
            float mx = fmaxf(fmaxf(s[i][0], s[i][1]), fmaxf(s[i][2], s[i][3]));
            mx = fmaxf(mx, __shfl_xor(mx, 1, 16));
            mx = fmaxf(mx, __shfl_xor(mx, 2, 16));
            mx = fmaxf(mx, __shfl_xor(mx, 4, 16));
            mx = fmaxf(mx, __shfl_xor(mx, 8, 16));
            const float newm = fmaxf(m_run[i], mx);
            const float fac = __expf(m_run[i] - newm);   // first iter: exp(-1e30)=0
            float rs = 0.f;
#pragma unroll
            for (int j = 0; j < 4; ++j) {
                const float p = __expf(s[i][j] - newm);
                s[i][j] = p;
                rs += p;
            }
            rs += __shfl_xor(rs, 1, 16);
            rs += __shfl_xor(rs, 2, 16);
            rs += __shfl_xor(rs, 4, 16);
            rs += __shfl_xor(rs, 8, 16);
            m_run[i] = newm;
            l_run[i] = l_run[i] * fac + rs;
            O[i][0] *= fac; O[i][1] *= fac; O[i][2] *= fac; O[i][3] *= fac;
        }

        // ---- stage P, then O += P @ V --------------------------------------
#pragma unroll
        for (int i = 0; i < 4; ++i) {
            const float4 p4 = make_float4(s[i][0], s[i][1], s[i][2], s[i][3]);
            *reinterpret_cast<float4*>(&Ps[ty * 4 + i][tx * 4]) = p4;
        }
        __syncthreads();

#pragma unroll
        for (int c0 = 0; c0 < 64; c0 += 4) {
            float4 p4[4], v4[4];
#pragma unroll
            for (int i = 0; i < 4; ++i)
                p4[i] = *reinterpret_cast<const float4*>(&Ps[ty * 4 + i][c0]);
#pragma unroll
            for (int u = 0; u < 4; ++u)
                v4[u] = *reinterpret_cast<const float4*>(&Vs[c0 + u][tx * 4]);
#pragma unroll
            for (int u = 0; u < 4; ++u) {
#pragma unroll
                for (int i = 0; i < 4; ++i) {
                    const float pv = reinterpret_cast<const float*>(&p4[i])[u];
                    O[i][0] = fmaf(pv, v4[u].x, O[i][0]);
                    O[i][1] = fmaf(pv, v4[u].y, O[i][1]);
                    O[i][2] = fmaf(pv, v4[u].z, O[i][2]);
                    O[i][3] = fmaf(pv, v4[u].w, O[i][3]);
                }
            }
        }
    }

    // ---- epilogue: attn_out [B,S,D] with col = h*HD + d ---------------------
#pragma unroll
    for (int i = 0; i < 4; ++i) {
        const float inv = 1.0f / l_run[i];
        const float4 ov = make_float4(O[i][0] * inv, O[i][1] * inv,
                                      O[i][2] * inv, O[i][3] * inv);
        const int srow = i0 + ty * 4 + i;
        float* dst = &o[((size_t)(b * SEQ + srow) * DIMSZ) + h * HD + tx * 4];
        *reinterpret_cast<float4*>(dst) = ov;
    }
}

// ---------------------------------------------------------------------------
extern "C" void kernel_launch(void* const* d_in, const int* in_sizes, int n_in,
                              void* d_out, int out_size, void* d_ws, size_t ws_size,
                              hipStream_t stream)
{
    const float* x  = (const float*)d_in[0];
    const float* wq = (const float*)d_in[1];
    const float* bq = (const float*)d_in[2];
    const float* wk = (const float*)d_in[3];
    const float* bk = (const float*)d_in[4];
    const float* wv = (const float*)d_in[5];
    const float* bv = (const float*)d_in[6];
    const float* wo = (const float*)d_in[7];
    const float* bo = (const float*)d_in[8];
    float* out = (float*)d_out;

    const size_t headElems = (size_t)BATCH * NH * SEQ * HD;  // 4,194,304 floats
    float* qws = (float*)d_ws;           // [B,H,S,hd]
    float* kws = qws + headElems;        // [B,H,S,hd]
    float* vws = kws + headElems;        // [B,H,S,hd]
    float* aws = vws + headElems;        // [B,S,D]  (attention output)

    const dim3 blk(256);
    const dim3 gproj(DIMSZ / 64, MTOT / 64);   // 16 x 64 tiles

    gemm_bias_kernel<0><<<gproj, blk, 0, stream>>>(x, wq, bq, qws, DIMSZ, DIMSZ);
    gemm_bias_kernel<0><<<gproj, blk, 0, stream>>>(x, wk, bk, kws, DIMSZ, DIMSZ);
    gemm_bias_kernel<0><<<gproj, blk, 0, stream>>>(x, wv, bv, vws, DIMSZ, DIMSZ);

    const dim3 gattn(SEQ / 64, NH, BATCH);     // 32 x 16 x 2 = 1024 blocks
    flash_attn_kernel<<<gattn, blk, 0, stream>>>(qws, kws, vws, aws);

    gemm_bias_kernel<1><<<gproj, blk, 0, stream>>>(aws, wo, bo, out, DIMSZ, DIMSZ);
}

// Round 4
// 270.205 us; speedup vs baseline: 4.5073x; 4.5073x over previous
//
#include <hip/hip_runtime.h>
#include <hip/hip_bf16.h>

// MHA: x[2,2048,1024] fp32 -> bf16 MFMA pipeline.
// SCALE=1/64 folded into q. Mask keeps j >= i (iterate j-tiles from diagonal up).
// Stages: cvt_x, cvt_w (transpose to W^T bf16), fused QKV MFMA GEMM (v stored
// transposed [B,H,hd,S]), MFMA flash attention, O-proj MFMA GEMM -> fp32.

constexpr int NH    = 16;
constexpr int HD    = 64;
constexpr int BATCH = 2;
constexpr int SEQ   = 2048;
constexpr int DIMSZ = 1024;
constexpr float SCALE = 1.0f / 64.0f;

typedef __attribute__((ext_vector_type(8))) short short8;
typedef __attribute__((ext_vector_type(4))) float f32x4;
typedef __attribute__((ext_vector_type(4))) unsigned short ushort4v;

__device__ inline unsigned short f2bf(float f) {
    __hip_bfloat16 h = __float2bfloat16(f);
    unsigned short u;
    __builtin_memcpy(&u, &h, 2);
    return u;
}

// ---------------------------------------------------------------------------
// x fp32 -> bf16, 8 elems/thread. grid 2048 x 256 covers 4096*1024 exactly.
// ---------------------------------------------------------------------------
__global__ __launch_bounds__(256) void cvt_x(const float* __restrict__ src,
                                             unsigned short* __restrict__ dst)
{
    const int i = blockIdx.x * 256 + threadIdx.x;
    const float4* s4 = reinterpret_cast<const float4*>(src);
    const float4 a = s4[(size_t)i * 2];
    const float4 b = s4[(size_t)i * 2 + 1];
    short8 o;
    o[0] = (short)f2bf(a.x); o[1] = (short)f2bf(a.y);
    o[2] = (short)f2bf(a.z); o[3] = (short)f2bf(a.w);
    o[4] = (short)f2bf(b.x); o[5] = (short)f2bf(b.y);
    o[6] = (short)f2bf(b.z); o[7] = (short)f2bf(b.w);
    *reinterpret_cast<short8*>(&dst[(size_t)i * 8]) = o;
}

// ---------------------------------------------------------------------------
// Weights: w[k][n] fp32 -> wt[which][n][k] bf16 (transposed). 64x64 LDS tiles.
// grid (16,16,4): x=n-tile, y=k-tile, z=which (q,k,v,o).
// ---------------------------------------------------------------------------
__global__ __launch_bounds__(256) void cvt_w(const float* __restrict__ wq,
                                             const float* __restrict__ wk,
                                             const float* __restrict__ wv,
                                             const float* __restrict__ wo,
                                             unsigned short* __restrict__ wt)
{
    __shared__ float tile[64][65];   // stride 65: 2-way-max banks on col reads
    const int t = threadIdx.x;
    const float* src = (blockIdx.z == 0) ? wq : (blockIdx.z == 1) ? wk
                     : (blockIdx.z == 2) ? wv : wo;
    const int n0 = blockIdx.x * 64, k0 = blockIdx.y * 64;

#pragma unroll
    for (int r = 0; r < 64; r += 16) {
        const int row = r + (t >> 4);
        const int c4 = (t & 15) * 4;
        const float4 v = *reinterpret_cast<const float4*>(
            &src[(size_t)(k0 + row) * DIMSZ + n0 + c4]);
        tile[row][c4 + 0] = v.x;  // scalar stores: stride 65 is not 16B-aligned
        tile[row][c4 + 1] = v.y;
        tile[row][c4 + 2] = v.z;
        tile[row][c4 + 3] = v.w;
    }
    __syncthreads();
#pragma unroll
    for (int rr = 0; rr < 2; ++rr) {
        const int n = rr * 32 + (t >> 3);
        const int kk0 = (t & 7) * 8;
        short8 pk;
#pragma unroll
        for (int e = 0; e < 8; ++e)
            pk[e] = (short)f2bf(tile[kk0 + e][n]);
        *reinterpret_cast<short8*>(
            &wt[((size_t)blockIdx.z * DIMSZ + n0 + n) * DIMSZ + k0 + kk0]) = pk;
    }
}

// ---------------------------------------------------------------------------
// MFMA GEMM: C = A[M,1024] @ W + bias, A bf16 row-major, Bt = W^T [N][1024] bf16.
// 128x128 tile, BK=64, 256 thr = 4 waves (2x2), 4x4 16x16 frags per wave.
// EPI 0: fused QKV epilogue (q scaled, [B,H,S,hd]; k [B,H,S,hd]; v [B,H,hd,S]).
// EPI 1: fp32 C[m][n] = acc + bias.
// ---------------------------------------------------------------------------
template <int EPI>
__global__ __launch_bounds__(256, 2) void mfma_gemm(
    const unsigned short* __restrict__ A, const unsigned short* __restrict__ Bt,
    const float* __restrict__ b0, const float* __restrict__ b1,
    const float* __restrict__ b2,
    unsigned short* __restrict__ q_o, unsigned short* __restrict__ k_o,
    unsigned short* __restrict__ vt_o, float* __restrict__ c_out)
{
    __shared__ unsigned short As[128 * 64];
    __shared__ unsigned short Bs[128 * 64];

    const int tid = threadIdx.x;
    const int lane = tid & 63;
    const int wv_ = tid >> 6;
    const int wr = wv_ >> 1, wc = wv_ & 1;
    const int c = lane & 15, g = lane >> 4;
    const int m0 = blockIdx.y * 128;
    const int nb0 = blockIdx.x * 128;

    f32x4 acc[4][4];
#pragma unroll
    for (int i = 0; i < 4; ++i)
#pragma unroll
        for (int j = 0; j < 4; ++j)
            acc[i][j] = (f32x4){0.f, 0.f, 0.f, 0.f};

    short8 sa[4], sb[4];
#pragma unroll
    for (int rr = 0; rr < 4; ++rr) {
        const int chunk = rr * 256 + tid;
        const int row = chunk >> 3, d0 = (chunk & 7) * 8;
        sa[rr] = *reinterpret_cast<const short8*>(&A[(size_t)(m0 + row) * DIMSZ + d0]);
        sb[rr] = *reinterpret_cast<const short8*>(&Bt[(size_t)(nb0 + row) * DIMSZ + d0]);
    }

    for (int kt = 0; kt < DIMSZ / 64; ++kt) {
        __syncthreads();
#pragma unroll
        for (int rr = 0; rr < 4; ++rr) {
            const int chunk = rr * 256 + tid;
            *reinterpret_cast<short8*>(&As[chunk * 8]) = sa[rr];
            *reinterpret_cast<short8*>(&Bs[chunk * 8]) = sb[rr];
        }
        __syncthreads();
        if (kt + 1 < DIMSZ / 64) {
            const int kof = (kt + 1) * 64;
#pragma unroll
            for (int rr = 0; rr < 4; ++rr) {
                const int chunk = rr * 256 + tid;
                const int row = chunk >> 3, d0 = (chunk & 7) * 8;
                sa[rr] = *reinterpret_cast<const short8*>(
                    &A[(size_t)(m0 + row) * DIMSZ + kof + d0]);
                sb[rr] = *reinterpret_cast<const short8*>(
                    &Bt[(size_t)(nb0 + row) * DIMSZ + kof + d0]);
            }
        }
#pragma unroll
        for (int kk = 0; kk < 2; ++kk) {
            short8 af[4], bfr[4];
#pragma unroll
            for (int mi = 0; mi < 4; ++mi)
                af[mi] = *reinterpret_cast<const short8*>(
                    &As[(wr * 64 + mi * 16 + c) * 64 + kk * 32 + g * 8]);
#pragma unroll
            for (int ni = 0; ni < 4; ++ni)
                bfr[ni] = *reinterpret_cast<const short8*>(
                    &Bs[(wc * 64 + ni * 16 + c) * 64 + kk * 32 + g * 8]);
#pragma unroll
            for (int mi = 0; mi < 4; ++mi)
#pragma unroll
                for (int ni = 0; ni < 4; ++ni)
                    acc[mi][ni] = __builtin_amdgcn_mfma_f32_16x16x32_bf16(
                        af[mi], bfr[ni], acc[mi][ni], 0, 0, 0);
        }
    }

    // ---- epilogue -----------------------------------------------------------
#pragma unroll
    for (int ni = 0; ni < 4; ++ni) {
        const int n_g = nb0 + wc * 64 + ni * 16 + c;
        if (EPI == 0) {
            const int which = n_g >> 10, nn = n_g & 1023;
            const int h = nn >> 6, d = nn & 63;
            const float bias = (which == 0 ? b0 : which == 1 ? b1 : b2)[nn];
#pragma unroll
            for (int mi = 0; mi < 4; ++mi) {
                const int m_g = m0 + wr * 64 + mi * 16 + g * 4;
                const int b = m_g >> 11, s = m_g & 2047;
                if (which == 0) {
#pragma unroll
                    for (int r = 0; r < 4; ++r)
                        q_o[((size_t)(b * NH + h) * SEQ + s + r) * HD + d] =
                            f2bf((acc[mi][ni][r] + bias) * SCALE);
                } else if (which == 1) {
#pragma unroll
                    for (int r = 0; r < 4; ++r)
                        k_o[((size_t)(b * NH + h) * SEQ + s + r) * HD + d] =
                            f2bf(acc[mi][ni][r] + bias);
                } else {
                    ushort4v pk;
#pragma unroll
                    for (int r = 0; r < 4; ++r)
                        pk[r] = f2bf(acc[mi][ni][r] + bias);
                    *reinterpret_cast<ushort4v*>(
                        &vt_o[((size_t)(b * NH + h) * HD + d) * SEQ + s]) = pk;
                }
            }
        } else {
            const float bias = b0[n_g];
#pragma unroll
            for (int mi = 0; mi < 4; ++mi) {
                const int m_g = m0 + wr * 64 + mi * 16 + g * 4;
#pragma unroll
                for (int r = 0; r < 4; ++r)
                    c_out[(size_t)(m_g + r) * DIMSZ + n_g] = acc[mi][ni][r] + bias;
            }
        }
    }
}

// ---------------------------------------------------------------------------
// MFMA flash attention. Block = 4 waves; wave w owns q-rows [i0+w*16, +16).
// K tile [64 key][64 d] and Vt tile [64 d][64 key] in LDS, stride 72 (bank pad).
// q pre-scaled by 1/64. Mask j >= i -> start at diagonal tile, mask only jt==qt.
// ---------------------------------------------------------------------------
__global__ __launch_bounds__(256, 2) void flash_mfma(
    const unsigned short* __restrict__ q, const unsigned short* __restrict__ k,
    const unsigned short* __restrict__ vt, unsigned short* __restrict__ o)
{
    constexpr int KS = 72;
    __shared__ unsigned short Ks[64 * KS];
    __shared__ unsigned short Vts[64 * KS];
    __shared__ unsigned short Ps[4][16 * KS];

    const int tid = threadIdx.x, lane = tid & 63, w = tid >> 6;
    const int c = lane & 15, g = lane >> 4;
    const int qt = blockIdx.x, h = blockIdx.y, b = blockIdx.z;
    const int head = b * NH + h;
    const unsigned short* kh = k + (size_t)head * SEQ * HD;
    const unsigned short* vth = vt + (size_t)head * HD * SEQ;
    const int i0 = qt * 64;

    short8 qa[2];
    {
        const size_t qbase = ((size_t)head * SEQ + i0 + w * 16 + c) * HD;
        qa[0] = *reinterpret_cast<const short8*>(&q[qbase + g * 8]);
        qa[1] = *reinterpret_cast<const short8*>(&q[qbase + 32 + g * 8]);
    }

    f32x4 accO[4];
    float m_run[4], l_run[4];
#pragma unroll
    for (int i = 0; i < 4; ++i) {
        accO[i] = (f32x4){0.f, 0.f, 0.f, 0.f};
        m_run[i] = -1e30f;
        l_run[i] = 0.f;
    }

    short8 kreg[2], vreg[2];
    {
        const int j0 = qt * 64;
#pragma unroll
        for (int rr = 0; rr < 2; ++rr) {
            const int chunk = rr * 256 + tid;
            const int row = chunk >> 3, d0 = (chunk & 7) * 8;
            kreg[rr] = *reinterpret_cast<const short8*>(&kh[(size_t)(j0 + row) * HD + d0]);
            vreg[rr] = *reinterpret_cast<const short8*>(&vth[(size_t)row * SEQ + j0 + d0]);
        }
    }

    for (int jt = qt; jt < SEQ / 64; ++jt) {
        __syncthreads();                    // prior tile's LDS reads complete
#pragma unroll
        for (int rr = 0; rr < 2; ++rr) {
            const int chunk = rr * 256 + tid;
            const int row = chunk >> 3, d0 = (chunk & 7) * 8;
            *reinterpret_cast<short8*>(&Ks[row * KS + d0]) = kreg[rr];
            *reinterpret_cast<short8*>(&Vts[row * KS + d0]) = vreg[rr];
        }
        __syncthreads();
        if (jt + 1 < SEQ / 64) {            // prefetch next tile under compute
            const int j0 = (jt + 1) * 64;
#pragma unroll
            for (int rr = 0; rr < 2; ++rr) {
                const int chunk = rr * 256 + tid;
                const int row = chunk >> 3, d0 = (chunk & 7) * 8;
                kreg[rr] = *reinterpret_cast<const short8*>(&kh[(size_t)(j0 + row) * HD + d0]);
                vreg[rr] = *reinterpret_cast<const short8*>(&vth[(size_t)row * SEQ + j0 + d0]);
            }
        }

        // ---- S = q_scaled @ K^T --------------------------------------------
        f32x4 sf[4];
#pragma unroll
        for (int ni = 0; ni < 4; ++ni) sf[ni] = (f32x4){0.f, 0.f, 0.f, 0.f};
#pragma unroll
        for (int kk = 0; kk < 2; ++kk) {
#pragma unroll
            for (int ni = 0; ni < 4; ++ni) {
                const short8 bkf = *reinterpret_cast<const short8*>(
                    &Ks[(ni * 16 + c) * KS + kk * 32 + g * 8]);
                sf[ni] = __builtin_amdgcn_mfma_f32_16x16x32_bf16(
                    qa[kk], bkf, sf[ni], 0, 0, 0);
            }
        }

        if (jt == qt) {
#pragma unroll
            for (int ni = 0; ni < 4; ++ni)
#pragma unroll
                for (int r = 0; r < 4; ++r) {
                    const int col = i0 + ni * 16 + c;
                    const int row_ = i0 + w * 16 + g * 4 + r;
                    if (col < row_) sf[ni][r] = -1e30f;
                }
        }

        // ---- online softmax (rows live on lane-group g, 16 lanes wide) -----
#pragma unroll
        for (int r = 0; r < 4; ++r) {
            float mx = fmaxf(fmaxf(sf[0][r], sf[1][r]), fmaxf(sf[2][r], sf[3][r]));
            mx = fmaxf(mx, __shfl_xor(mx, 1, 16));
            mx = fmaxf(mx, __shfl_xor(mx, 2, 16));
            mx = fmaxf(mx, __shfl_xor(mx, 4, 16));
            mx = fmaxf(mx, __shfl_xor(mx, 8, 16));
            const float newm = fmaxf(m_run[r], mx);
            const float fac = __expf(m_run[r] - newm);
            float rs = 0.f;
#pragma unroll
            for (int ni = 0; ni < 4; ++ni) {
                const float p = __expf(sf[ni][r] - newm);
                sf[ni][r] = p;
                rs += p;
            }
            rs += __shfl_xor(rs, 1, 16);
            rs += __shfl_xor(rs, 2, 16);
            rs += __shfl_xor(rs, 4, 16);
            rs += __shfl_xor(rs, 8, 16);
            m_run[r] = newm;
            l_run[r] = l_run[r] * fac + rs;
#pragma unroll
            for (int ni = 0; ni < 4; ++ni) accO[ni][r] *= fac;
        }

        // ---- stage P (per-wave buffer; same-wave LDS ordering, no barrier) --
#pragma unroll
        for (int ni = 0; ni < 4; ++ni)
#pragma unroll
            for (int r = 0; r < 4; ++r)
                Ps[w][(g * 4 + r) * KS + ni * 16 + c] = f2bf(sf[ni][r]);

        // ---- O += P @ V ----------------------------------------------------
#pragma unroll
        for (int kk = 0; kk < 2; ++kk) {
            const short8 pa = *reinterpret_cast<const short8*>(
                &Ps[w][c * KS + kk * 32 + g * 8]);
#pragma unroll
            for (int ni = 0; ni < 4; ++ni) {
                const short8 vb = *reinterpret_cast<const short8*>(
                    &Vts[(ni * 16 + c) * KS + kk * 32 + g * 8]);
                accO[ni] = __builtin_amdgcn_mfma_f32_16x16x32_bf16(
                    pa, vb, accO[ni], 0, 0, 0);
            }
        }
    }

    // ---- epilogue: o[B,S,D] bf16, col = h*64 + d ----------------------------
#pragma unroll
    for (int ni = 0; ni < 4; ++ni)
#pragma unroll
        for (int r = 0; r < 4; ++r) {
            const int row_ = i0 + w * 16 + g * 4 + r;
            const int d = ni * 16 + c;
            o[((size_t)b * SEQ + row_) * DIMSZ + h * HD + d] =
                f2bf(accO[ni][r] / l_run[r]);
        }
}

// ---------------------------------------------------------------------------
extern "C" void kernel_launch(void* const* d_in, const int* in_sizes, int n_in,
                              void* d_out, int out_size, void* d_ws, size_t ws_size,
                              hipStream_t stream)
{
    const float* x  = (const float*)d_in[0];
    const float* wq = (const float*)d_in[1];
    const float* bq = (const float*)d_in[2];
    const float* wk = (const float*)d_in[3];
    const float* bk = (const float*)d_in[4];
    const float* wv = (const float*)d_in[5];
    const float* bv = (const float*)d_in[6];
    const float* wo = (const float*)d_in[7];
    const float* bo = (const float*)d_in[8];
    float* out = (float*)d_out;

    const size_t M4 = (size_t)4 * 1024 * 1024;
    unsigned short* p = (unsigned short*)d_ws;
    unsigned short* x_bf  = p;           // [4096][1024]
    unsigned short* wt    = p + M4;      // [4][1024][1024]  (q,k,v,o transposed)
    unsigned short* q_bf  = p + 2 * M4;  // [B,H,S,hd], pre-scaled
    unsigned short* k_bf  = p + 3 * M4;  // [B,H,S,hd]
    unsigned short* vt_bf = p + 4 * M4;  // [B,H,hd,S]
    unsigned short* abf   = p + 5 * M4;  // [4096][1024] attn out
    // 48 MB total

    cvt_x<<<2048, 256, 0, stream>>>(x, x_bf);
    cvt_w<<<dim3(16, 16, 4), 256, 0, stream>>>(wq, wk, wv, wo, wt);

    mfma_gemm<0><<<dim3(24, 32), 256, 0, stream>>>(
        x_bf, wt, bq, bk, bv, q_bf, k_bf, vt_bf, nullptr);

    flash_mfma<<<dim3(32, 16, 2), 256, 0, stream>>>(q_bf, k_bf, vt_bf, abf);

    mfma_gemm<1><<<dim3(8, 32), 256, 0, stream>>>(
        abf, wt + (size_t)3 * 1024 * 1024, bo, nullptr, nullptr,
        nullptr, nullptr, nullptr, out);
}

// Round 9
// 228.071 us; speedup vs baseline: 5.3400x; 1.1847x over previous
//
#include <hip/hip_runtime.h>
#include <hip/hip_bf16.h>

// MHA: x[2,2048,1024] fp32 -> bf16 MFMA pipeline.
// R5: flash load-balance pairing (qt, 31-qt), exp2-domain softmax, setprio,
//     GEMM staging via global_load_lds (double-buffered, m97 pattern).

constexpr int NH    = 16;
constexpr int HD    = 64;
constexpr int BATCH = 2;
constexpr int SEQ   = 2048;
constexpr int DIMSZ = 1024;
constexpr float SCALE = 1.0f / 64.0f;
constexpr float QSCL = SCALE * 1.44269504088896f;   // fold log2(e): softmax in exp2 domain

typedef __attribute__((ext_vector_type(8))) short short8;
typedef __attribute__((ext_vector_type(4))) float f32x4;
typedef __attribute__((ext_vector_type(4))) unsigned short ushort4v;

__device__ inline unsigned short f2bf(float f) {
    __hip_bfloat16 h = __float2bfloat16(f);
    unsigned short u;
    __builtin_memcpy(&u, &h, 2);
    return u;
}

// async global->LDS, 16B per lane; LDS dest is wave-uniform base + lane*16.
__device__ __forceinline__ void gload_lds16(const void* g, void* l) {
    __builtin_amdgcn_global_load_lds(
        (const __attribute__((address_space(1))) unsigned int*)g,
        (__attribute__((address_space(3))) unsigned int*)l, 16, 0, 0);
}

// ---------------------------------------------------------------------------
// x fp32 -> bf16, 8 elems/thread.
// ---------------------------------------------------------------------------
__global__ __launch_bounds__(256) void cvt_x(const float* __restrict__ src,
                                             unsigned short* __restrict__ dst)
{
    const int i = blockIdx.x * 256 + threadIdx.x;
    const float4* s4 = reinterpret_cast<const float4*>(src);
    const float4 a = s4[(size_t)i * 2];
    const float4 b = s4[(size_t)i * 2 + 1];
    short8 o;
    o[0] = (short)f2bf(a.x); o[1] = (short)f2bf(a.y);
    o[2] = (short)f2bf(a.z); o[3] = (short)f2bf(a.w);
    o[4] = (short)f2bf(b.x); o[5] = (short)f2bf(b.y);
    o[6] = (short)f2bf(b.z); o[7] = (short)f2bf(b.w);
    *reinterpret_cast<short8*>(&dst[(size_t)i * 8]) = o;
}

// ---------------------------------------------------------------------------
// Weights: w[k][n] fp32 -> wt[which][n][k] bf16 (transposed). 64x64 LDS tiles.
// ---------------------------------------------------------------------------
__global__ __launch_bounds__(256) void cvt_w(const float* __restrict__ wq,
                                             const float* __restrict__ wk,
                                             const float* __restrict__ wv,
                                             const float* __restrict__ wo,
                                             unsigned short* __restrict__ wt)
{
    __shared__ float tile[64][65];
    const int t = threadIdx.x;
    const float* src = (blockIdx.z == 0) ? wq : (blockIdx.z == 1) ? wk
                     : (blockIdx.z == 2) ? wv : wo;
    const int n0 = blockIdx.x * 64, k0 = blockIdx.y * 64;

#pragma unroll
    for (int r = 0; r < 64; r += 16) {
        const int row = r + (t >> 4);
        const int c4 = (t & 15) * 4;
        const float4 v = *reinterpret_cast<const float4*>(
            &src[(size_t)(k0 + row) * DIMSZ + n0 + c4]);
        tile[row][c4 + 0] = v.x;
        tile[row][c4 + 1] = v.y;
        tile[row][c4 + 2] = v.z;
        tile[row][c4 + 3] = v.w;
    }
    __syncthreads();
#pragma unroll
    for (int rr = 0; rr < 2; ++rr) {
        const int n = rr * 32 + (t >> 3);
        const int kk0 = (t & 7) * 8;
        short8 pk;
#pragma unroll
        for (int e = 0; e < 8; ++e)
            pk[e] = (short)f2bf(tile[kk0 + e][n]);
        *reinterpret_cast<short8*>(
            &wt[((size_t)blockIdx.z * DIMSZ + n0 + n) * DIMSZ + k0 + kk0]) = pk;
    }
}

// ---------------------------------------------------------------------------
// MFMA GEMM, global_load_lds staging, double-buffered LDS, 1 barrier/K-step.
// 128x128 tile, BK=64, 4 waves (2x2), 4x4 16x16x32 frags per wave.
// EPI 0: fused QKV epilogue (q scaled by QSCL, [B,H,S,hd]; k; v -> [B,H,hd,S]).
// EPI 1: fp32 C = acc + bias.
// ---------------------------------------------------------------------------
template <int EPI>
__global__ __launch_bounds__(256, 2) void mfma_gemm(
    const unsigned short* __restrict__ A, const unsigned short* __restrict__ Bt,
    const float* __restrict__ b0, const float* __restrict__ b1,
    const float* __restrict__ b2,
    unsigned short* __restrict__ q_o, unsigned short* __restrict__ k_o,
    unsigned short* __restrict__ vt_o, float* __restrict__ c_out)
{
    __shared__ unsigned short As[2][128 * 64];
    __shared__ unsigned short Bs[2][128 * 64];

    const int tid = threadIdx.x;
    const int lane = tid & 63;
    const int wv_ = tid >> 6;
    const int wr = wv_ >> 1, wc = wv_ & 1;
    const int c = lane & 15, g = lane >> 4;
    const int m0 = blockIdx.y * 128;
    const int nb0 = blockIdx.x * 128;
    const int wbase = (tid & 192) * 8;        // wave-uniform LDS u16 offset
    const int lrow = tid >> 3, ld0 = (tid & 7) * 8;

    f32x4 acc[4][4];
#pragma unroll
    for (int i = 0; i < 4; ++i)
#pragma unroll
        for (int j = 0; j < 4; ++j)
            acc[i][j] = (f32x4){0.f, 0.f, 0.f, 0.f};

    // issue 4 chunks per matrix: chunk = it*256 + tid covers 128x64 tile
    auto issue = [&](unsigned short* dA, unsigned short* dB, int k0) {
#pragma unroll
        for (int it = 0; it < 4; ++it) {
            const int row = it * 32 + lrow;
            gload_lds16(&A[(size_t)(m0 + row) * DIMSZ + k0 + ld0],
                        &dA[it * 2048 + wbase]);
            gload_lds16(&Bt[(size_t)(nb0 + row) * DIMSZ + k0 + ld0],
                        &dB[it * 2048 + wbase]);
        }
    };

    auto compute = [&](const unsigned short* Ac, const unsigned short* Bc) {
#pragma unroll
        for (int kk = 0; kk < 2; ++kk) {
            short8 af[4], bfr[4];
#pragma unroll
            for (int mi = 0; mi < 4; ++mi)
                af[mi] = *reinterpret_cast<const short8*>(
                    &Ac[(wr * 64 + mi * 16 + c) * 64 + kk * 32 + g * 8]);
#pragma unroll
            for (int ni = 0; ni < 4; ++ni)
                bfr[ni] = *reinterpret_cast<const short8*>(
                    &Bc[(wc * 64 + ni * 16 + c) * 64 + kk * 32 + g * 8]);
            __builtin_amdgcn_s_setprio(1);
#pragma unroll
            for (int mi = 0; mi < 4; ++mi)
#pragma unroll
                for (int ni = 0; ni < 4; ++ni)
                    acc[mi][ni] = __builtin_amdgcn_mfma_f32_16x16x32_bf16(
                        af[mi], bfr[ni], acc[mi][ni], 0, 0, 0);
            __builtin_amdgcn_s_setprio(0);
        }
    };

    issue(As[0], Bs[0], 0);
#pragma unroll 1
    for (int kt = 0; kt < DIMSZ / 64; kt += 2) {
        __syncthreads();                       // drains own vmcnt -> buf0 ready
        if (kt + 1 < DIMSZ / 64) issue(As[1], Bs[1], (kt + 1) * 64);
        compute(As[0], Bs[0]);
        __syncthreads();                       // buf1 ready
        if (kt + 2 < DIMSZ / 64) issue(As[0], Bs[0], (kt + 2) * 64);
        compute(As[1], Bs[1]);
    }

    // ---- epilogue -----------------------------------------------------------
#pragma unroll
    for (int ni = 0; ni < 4; ++ni) {
        const int n_g = nb0 + wc * 64 + ni * 16 + c;
        if (EPI == 0) {
            const int which = n_g >> 10, nn = n_g & 1023;
            const int h = nn >> 6, d = nn & 63;
            const float bias = (which == 0 ? b0 : which == 1 ? b1 : b2)[nn];
#pragma unroll
            for (int mi = 0; mi < 4; ++mi) {
                const int m_g = m0 + wr * 64 + mi * 16 + g * 4;
                const int b = m_g >> 11, s = m_g & 2047;
                if (which == 0) {
#pragma unroll
                    for (int r = 0; r < 4; ++r)
                        q_o[((size_t)(b * NH + h) * SEQ + s + r) * HD + d] =
                            f2bf((acc[mi][ni][r] + bias) * QSCL);
                } else if (which == 1) {
#pragma unroll
                    for (int r = 0; r < 4; ++r)
                        k_o[((size_t)(b * NH + h) * SEQ + s + r) * HD + d] =
                            f2bf(acc[mi][ni][r] + bias);
                } else {
                    ushort4v pk;
#pragma unroll
                    for (int r = 0; r < 4; ++r)
                        pk[r] = f2bf(acc[mi][ni][r] + bias);
                    *reinterpret_cast<ushort4v*>(
                        &vt_o[((size_t)(b * NH + h) * HD + d) * SEQ + s]) = pk;
                }
            }
        } else {
            const float bias = b0[n_g];
#pragma unroll
            for (int mi = 0; mi < 4; ++mi) {
                const int m_g = m0 + wr * 64 + mi * 16 + g * 4;
#pragma unroll
                for (int r = 0; r < 4; ++r)
                    c_out[(size_t)(m_g + r) * DIMSZ + n_g] = acc[mi][ni][r] + bias;
            }
        }
    }
}

// ---------------------------------------------------------------------------
// Flash attention tile step: S=q@K^T (exp2 domain), online softmax, O += P@V.
// Wave owns 16 q-rows; P staged per-wave (same-wave LDS ordering, no barrier).
// ---------------------------------------------------------------------------
__device__ __forceinline__ void attn_tile(
    const short8 (&qa)[2], f32x4 (&accO)[4], float (&m_run)[4], float (&l_run)[4],
    const unsigned short* Ks, const unsigned short* Vts, unsigned short* Psw,
    const int c, const int g, const int w, const bool masked)
{
    constexpr int KS = 72;
    f32x4 sf[4];
#pragma unroll
    for (int ni = 0; ni < 4; ++ni) sf[ni] = (f32x4){0.f, 0.f, 0.f, 0.f};

    __builtin_amdgcn_s_setprio(1);
#pragma unroll
    for (int kk = 0; kk < 2; ++kk)
#pragma unroll
        for (int ni = 0; ni < 4; ++ni) {
            const short8 bkf = *reinterpret_cast<const short8*>(
                &Ks[(ni * 16 + c) * KS + kk * 32 + g * 8]);
            sf[ni] = __builtin_amdgcn_mfma_f32_16x16x32_bf16(
                qa[kk], bkf, sf[ni], 0, 0, 0);
        }
    __builtin_amdgcn_s_setprio(0);

    if (masked) {                 // diagonal tile: keep col >= row (relative)
#pragma unroll
        for (int ni = 0; ni < 4; ++ni)
#pragma unroll
            for (int r = 0; r < 4; ++r)
                if (ni * 16 + c < w * 16 + g * 4 + r) sf[ni][r] = -1e30f;
    }

#pragma unroll
    for (int r = 0; r < 4; ++r) {
        float mx = fmaxf(fmaxf(sf[0][r], sf[1][r]), fmaxf(sf[2][r], sf[3][r]));
        mx = fmaxf(mx, __shfl_xor(mx, 1, 16));
        mx = fmaxf(mx, __shfl_xor(mx, 2, 16));
        mx = fmaxf(mx, __shfl_xor(mx, 4, 16));
        mx = fmaxf(mx, __shfl_xor(mx, 8, 16));
        const float newm = fmaxf(m_run[r], mx);
        const float fac = exp2f(m_run[r] - newm);
        float rs = 0.f;
#pragma unroll
        for (int ni = 0; ni < 4; ++ni) {
            const float p = exp2f(sf[ni][r] - newm);
            sf[ni][r] = p;
            rs += p;
        }
        rs += __shfl_xor(rs, 1, 16);
        rs += __shfl_xor(rs, 2, 16);
        rs += __shfl_xor(rs, 4, 16);
        rs += __shfl_xor(rs, 8, 16);
        m_run[r] = newm;
        l_run[r] = l_run[r] * fac + rs;
#pragma unroll
        for (int ni = 0; ni < 4; ++ni) accO[ni][r] *= fac;
    }

#pragma unroll
    for (int ni = 0; ni < 4; ++ni)
#pragma unroll
        for (int r = 0; r < 4; ++r)
            Psw[(g * 4 + r) * KS + ni * 16 + c] = f2bf(sf[ni][r]);

    __builtin_amdgcn_s_setprio(1);
#pragma unroll
    for (int kk = 0; kk < 2; ++kk) {
        const short8 pa = *reinterpret_cast<const short8*>(
            &Psw[c * KS + kk * 32 + g * 8]);
#pragma unroll
        for (int ni = 0; ni < 4; ++ni) {
            const short8 vb = *reinterpret_cast<const short8*>(
                &Vts[(ni * 16 + c) * KS + kk * 32 + g * 8]);
            accO[ni] = __builtin_amdgcn_mfma_f32_16x16x32_bf16(
                pa, vb, accO[ni], 0, 0, 0);
        }
    }
    __builtin_amdgcn_s_setprio(0);
}

// ---------------------------------------------------------------------------
// Paired flash attention: block x handles qt1=x and qt2=31-x (33 tiles each,
// perfectly balanced). One j-loop from qt1; q2 active when jt >= qt2.
// ---------------------------------------------------------------------------
__global__ __launch_bounds__(256, 2) void flash_mfma(
    const unsigned short* __restrict__ q, const unsigned short* __restrict__ k,
    const unsigned short* __restrict__ vt, unsigned short* __restrict__ o)
{
    constexpr int KS = 72;
    __shared__ unsigned short Ks[64 * KS];
    __shared__ unsigned short Vts[64 * KS];
    __shared__ unsigned short Ps[4][16 * KS];

    const int tid = threadIdx.x, lane = tid & 63, w = tid >> 6;
    const int c = lane & 15, g = lane >> 4;
    const int qt1 = blockIdx.x;          // 0..15
    const int qt2 = 31 - qt1;            // 31..16
    const int h = blockIdx.y, b = blockIdx.z;
    const int head = b * NH + h;
    const unsigned short* kh = k + (size_t)head * SEQ * HD;
    const unsigned short* vth = vt + (size_t)head * HD * SEQ;
    unsigned short* Psw = &Ps[w][0];

    short8 qa1[2], qa2[2];
    {
        const size_t qb1 = ((size_t)head * SEQ + qt1 * 64 + w * 16 + c) * HD;
        qa1[0] = *reinterpret_cast<const short8*>(&q[qb1 + g * 8]);
        qa1[1] = *reinterpret_cast<const short8*>(&q[qb1 + 32 + g * 8]);
        const size_t qb2 = ((size_t)head * SEQ + qt2 * 64 + w * 16 + c) * HD;
        qa2[0] = *reinterpret_cast<const short8*>(&q[qb2 + g * 8]);
        qa2[1] = *reinterpret_cast<const short8*>(&q[qb2 + 32 + g * 8]);
    }

    f32x4 acc1[4], acc2[4];
    float m1[4], l1[4], m2[4], l2[4];
#pragma unroll
    for (int i = 0; i < 4; ++i) {
        acc1[i] = (f32x4){0.f, 0.f, 0.f, 0.f};
        acc2[i] = (f32x4){0.f, 0.f, 0.f, 0.f};
        m1[i] = -1e30f; l1[i] = 0.f;
        m2[i] = -1e30f; l2[i] = 0.f;
    }

    short8 kreg[2], vreg[2];
    {
        const int j0 = qt1 * 64;
#pragma unroll
        for (int rr = 0; rr < 2; ++rr) {
            const int chunk = rr * 256 + tid;
            const int row = chunk >> 3, d0 = (chunk & 7) * 8;
            kreg[rr] = *reinterpret_cast<const short8*>(&kh[(size_t)(j0 + row) * HD + d0]);
            vreg[rr] = *reinterpret_cast<const short8*>(&vth[(size_t)row * SEQ + j0 + d0]);
        }
    }

    for (int jt = qt1; jt < SEQ / 64; ++jt) {
        __syncthreads();                 // prior tile's LDS reads complete
#pragma unroll
        for (int rr = 0; rr < 2; ++rr) {
            const int chunk = rr * 256 + tid;
            const int row = chunk >> 3, d0 = (chunk & 7) * 8;
            *reinterpret_cast<short8*>(&Ks[row * KS + d0]) = kreg[rr];
            *reinterpret_cast<short8*>(&Vts[row * KS + d0]) = vreg[rr];
        }
        __syncthreads();
        if (jt + 1 < SEQ / 64) {         // prefetch next tile under compute
            const int j0 = (jt + 1) * 64;
#pragma unroll
            for (int rr = 0; rr < 2; ++rr) {
                const int chunk = rr * 256 + tid;
                const int row = chunk >> 3, d0 = (chunk & 7) * 8;
                kreg[rr] = *reinterpret_cast<const short8*>(&kh[(size_t)(j0 + row) * HD + d0]);
                vreg[rr] = *reinterpret_cast<const short8*>(&vth[(size_t)row * SEQ + j0 + d0]);
            }
        }

        attn_tile(qa1, acc1, m1, l1, Ks, Vts, Psw, c, g, w, jt == qt1);
        if (jt >= qt2)
            attn_tile(qa2, acc2, m2, l2, Ks, Vts, Psw, c, g, w, jt == qt2);
    }

    // ---- epilogue: o[B,S,D] bf16, col = h*64 + d ----------------------------
#pragma unroll
    for (int ni = 0; ni < 4; ++ni)
#pragma unroll
        for (int r = 0; r < 4; ++r) {
            const int d = ni * 16 + c;
            const int r1 = qt1 * 64 + w * 16 + g * 4 + r;
            o[((size_t)b * SEQ + r1) * DIMSZ + h * HD + d] =
                f2bf(acc1[ni][r] / l1[r]);
            const int r2 = qt2 * 64 + w * 16 + g * 4 + r;
            o[((size_t)b * SEQ + r2) * DIMSZ + h * HD + d] =
                f2bf(acc2[ni][r] / l2[r]);
        }
}

// ---------------------------------------------------------------------------
extern "C" void kernel_launch(void* const* d_in, const int* in_sizes, int n_in,
                              void* d_out, int out_size, void* d_ws, size_t ws_size,
                              hipStream_t stream)
{
    const float* x  = (const float*)d_in[0];
    const float* wq = (const float*)d_in[1];
    const float* bq = (const float*)d_in[2];
    const float* wk = (const float*)d_in[3];
    const float* bk = (const float*)d_in[4];
    const float* wv = (const float*)d_in[5];
    const float* bv = (const float*)d_in[6];
    const float* wo = (const float*)d_in[7];
    const float* bo = (const float*)d_in[8];
    float* out = (float*)d_out;

    const size_t M4 = (size_t)4 * 1024 * 1024;
    unsigned short* p = (unsigned short*)d_ws;
    unsigned short* x_bf  = p;           // [4096][1024]
    unsigned short* wt    = p + M4;      // [4][1024][1024]
    unsigned short* q_bf  = p + 2 * M4;  // [B,H,S,hd], pre-scaled by QSCL
    unsigned short* k_bf  = p + 3 * M4;  // [B,H,S,hd]
    unsigned short* vt_bf = p + 4 * M4;  // [B,H,hd,S]
    unsigned short* abf   = p + 5 * M4;  // [4096][1024]

    cvt_x<<<2048, 256, 0, stream>>>(x, x_bf);
    cvt_w<<<dim3(16, 16, 4), 256, 0, stream>>>(wq, wk, wv, wo, wt);

    mfma_gemm<0><<<dim3(24, 32), 256, 0, stream>>>(
        x_bf, wt, bq, bk, bv, q_bf, k_bf, vt_bf, nullptr);

    flash_mfma<<<dim3(16, 16, 2), 256, 0, stream>>>(q_bf, k_bf, vt_bf, abf);

    mfma_gemm<1><<<dim3(8, 32), 256, 0, stream>>>(
        abf, wt + (size_t)3 * 1024 * 1024, bo, nullptr, nullptr,
        nullptr, nullptr, nullptr, out);
}

// Round 10
// 211.605 us; speedup vs baseline: 5.7555x; 1.0778x over previous
//
#include <hip/hip_runtime.h>
#include <hip/hip_bf16.h>

// MHA: x[2,2048,1024] fp32 -> bf16 MFMA pipeline.
// R10: flash swapped-QK^T (S^T = K@Q^T) -> in-register softmax (lane owns a
//      q-row; 4 shuffles/tile instead of 32; P packed in-register via
//      v_cvt_pk_bf16_f32, no LDS P staging). GEMMs/cvt unchanged from R9.

constexpr int NH    = 16;
constexpr int HD    = 64;
constexpr int BATCH = 2;
constexpr int SEQ   = 2048;
constexpr int DIMSZ = 1024;
constexpr float SCALE = 1.0f / 64.0f;
constexpr float QSCL = SCALE * 1.44269504088896f;   // fold log2(e): softmax in exp2 domain

typedef __attribute__((ext_vector_type(8))) short short8;
typedef __attribute__((ext_vector_type(4))) short short4v;
typedef __attribute__((ext_vector_type(4))) float f32x4;
typedef __attribute__((ext_vector_type(4))) unsigned short ushort4v;

__device__ inline unsigned short f2bf(float f) {
    __hip_bfloat16 h = __float2bfloat16(f);
    unsigned short u;
    __builtin_memcpy(&u, &h, 2);
    return u;
}

__device__ __forceinline__ unsigned int cvt_pk_bf16(float lo, float hi) {
    unsigned int r;
    asm("v_cvt_pk_bf16_f32 %0, %1, %2" : "=v"(r) : "v"(lo), "v"(hi));
    return r;
}

// async global->LDS, 16B per lane; LDS dest is wave-uniform base + lane*16.
__device__ __forceinline__ void gload_lds16(const void* g, void* l) {
    __builtin_amdgcn_global_load_lds(
        (const __attribute__((address_space(1))) unsigned int*)g,
        (__attribute__((address_space(3))) unsigned int*)l, 16, 0, 0);
}

// ---------------------------------------------------------------------------
// x fp32 -> bf16, 8 elems/thread.
// ---------------------------------------------------------------------------
__global__ __launch_bounds__(256) void cvt_x(const float* __restrict__ src,
                                             unsigned short* __restrict__ dst)
{
    const int i = blockIdx.x * 256 + threadIdx.x;
    const float4* s4 = reinterpret_cast<const float4*>(src);
    const float4 a = s4[(size_t)i * 2];
    const float4 b = s4[(size_t)i * 2 + 1];
    short8 o;
    o[0] = (short)f2bf(a.x); o[1] = (short)f2bf(a.y);
    o[2] = (short)f2bf(a.z); o[3] = (short)f2bf(a.w);
    o[4] = (short)f2bf(b.x); o[5] = (short)f2bf(b.y);
    o[6] = (short)f2bf(b.z); o[7] = (short)f2bf(b.w);
    *reinterpret_cast<short8*>(&dst[(size_t)i * 8]) = o;
}

// ---------------------------------------------------------------------------
// Weights: w[k][n] fp32 -> wt[which][n][k] bf16 (transposed). 64x64 LDS tiles.
// ---------------------------------------------------------------------------
__global__ __launch_bounds__(256) void cvt_w(const float* __restrict__ wq,
                                             const float* __restrict__ wk,
                                             const float* __restrict__ wv,
                                             const float* __restrict__ wo,
                                             unsigned short* __restrict__ wt)
{
    __shared__ float tile[64][65];
    const int t = threadIdx.x;
    const float* src = (blockIdx.z == 0) ? wq : (blockIdx.z == 1) ? wk
                     : (blockIdx.z == 2) ? wv : wo;
    const int n0 = blockIdx.x * 64, k0 = blockIdx.y * 64;

#pragma unroll
    for (int r = 0; r < 64; r += 16) {
        const int row = r + (t >> 4);
        const int c4 = (t & 15) * 4;
        const float4 v = *reinterpret_cast<const float4*>(
            &src[(size_t)(k0 + row) * DIMSZ + n0 + c4]);
        tile[row][c4 + 0] = v.x;
        tile[row][c4 + 1] = v.y;
        tile[row][c4 + 2] = v.z;
        tile[row][c4 + 3] = v.w;
    }
    __syncthreads();
#pragma unroll
    for (int rr = 0; rr < 2; ++rr) {
        const int n = rr * 32 + (t >> 3);
        const int kk0 = (t & 7) * 8;
        short8 pk;
#pragma unroll
        for (int e = 0; e < 8; ++e)
            pk[e] = (short)f2bf(tile[kk0 + e][n]);
        *reinterpret_cast<short8*>(
            &wt[((size_t)blockIdx.z * DIMSZ + n0 + n) * DIMSZ + k0 + kk0]) = pk;
    }
}

// ---------------------------------------------------------------------------
// MFMA GEMM, global_load_lds staging, double-buffered LDS, 1 barrier/K-step.
// 128x128 tile, BK=64, 4 waves (2x2), 4x4 16x16x32 frags per wave.
// EPI 0: fused QKV epilogue (q scaled by QSCL, [B,H,S,hd]; k; v -> [B,H,hd,S]).
// EPI 1: fp32 C = acc + bias.
// ---------------------------------------------------------------------------
template <int EPI>
__global__ __launch_bounds__(256, 2) void mfma_gemm(
    const unsigned short* __restrict__ A, const unsigned short* __restrict__ Bt,
    const float* __restrict__ b0, const float* __restrict__ b1,
    const float* __restrict__ b2,
    unsigned short* __restrict__ q_o, unsigned short* __restrict__ k_o,
    unsigned short* __restrict__ vt_o, float* __restrict__ c_out)
{
    __shared__ unsigned short As[2][128 * 64];
    __shared__ unsigned short Bs[2][128 * 64];

    const int tid = threadIdx.x;
    const int lane = tid & 63;
    const int wv_ = tid >> 6;
    const int wr = wv_ >> 1, wc = wv_ & 1;
    const int c = lane & 15, g = lane >> 4;
    const int m0 = blockIdx.y * 128;
    const int nb0 = blockIdx.x * 128;
    const int wbase = (tid & 192) * 8;        // wave-uniform LDS u16 offset
    const int lrow = tid >> 3, ld0 = (tid & 7) * 8;

    f32x4 acc[4][4];
#pragma unroll
    for (int i = 0; i < 4; ++i)
#pragma unroll
        for (int j = 0; j < 4; ++j)
            acc[i][j] = (f32x4){0.f, 0.f, 0.f, 0.f};

    // issue 4 chunks per matrix: chunk = it*256 + tid covers 128x64 tile
    auto issue = [&](unsigned short* dA, unsigned short* dB, int k0) {
#pragma unroll
        for (int it = 0; it < 4; ++it) {
            const int row = it * 32 + lrow;
            gload_lds16(&A[(size_t)(m0 + row) * DIMSZ + k0 + ld0],
                        &dA[it * 2048 + wbase]);
            gload_lds16(&Bt[(size_t)(nb0 + row) * DIMSZ + k0 + ld0],
                        &dB[it * 2048 + wbase]);
        }
    };

    auto compute = [&](const unsigned short* Ac, const unsigned short* Bc) {
#pragma unroll
        for (int kk = 0; kk < 2; ++kk) {
            short8 af[4], bfr[4];
#pragma unroll
            for (int mi = 0; mi < 4; ++mi)
                af[mi] = *reinterpret_cast<const short8*>(
                    &Ac[(wr * 64 + mi * 16 + c) * 64 + kk * 32 + g * 8]);
#pragma unroll
            for (int ni = 0; ni < 4; ++ni)
                bfr[ni] = *reinterpret_cast<const short8*>(
                    &Bc[(wc * 64 + ni * 16 + c) * 64 + kk * 32 + g * 8]);
            __builtin_amdgcn_s_setprio(1);
#pragma unroll
            for (int mi = 0; mi < 4; ++mi)
#pragma unroll
                for (int ni = 0; ni < 4; ++ni)
                    acc[mi][ni] = __builtin_amdgcn_mfma_f32_16x16x32_bf16(
                        af[mi], bfr[ni], acc[mi][ni], 0, 0, 0);
            __builtin_amdgcn_s_setprio(0);
        }
    };

    issue(As[0], Bs[0], 0);
#pragma unroll 1
    for (int kt = 0; kt < DIMSZ / 64; kt += 2) {
        __syncthreads();                       // drains own vmcnt -> buf0 ready
        if (kt + 1 < DIMSZ / 64) issue(As[1], Bs[1], (kt + 1) * 64);
        compute(As[0], Bs[0]);
        __syncthreads();                       // buf1 ready
        if (kt + 2 < DIMSZ / 64) issue(As[0], Bs[0], (kt + 2) * 64);
        compute(As[1], Bs[1]);
    }

    // ---- epilogue -----------------------------------------------------------
#pragma unroll
    for (int ni = 0; ni < 4; ++ni) {
        const int n_g = nb0 + wc * 64 + ni * 16 + c;
        if (EPI == 0) {
            const int which = n_g >> 10, nn = n_g & 1023;
            const int h = nn >> 6, d = nn & 63;
            const float bias = (which == 0 ? b0 : which == 1 ? b1 : b2)[nn];
#pragma unroll
            for (int mi = 0; mi < 4; ++mi) {
                const int m_g = m0 + wr * 64 + mi * 16 + g * 4;
                const int b = m_g >> 11, s = m_g & 2047;
                if (which == 0) {
#pragma unroll
                    for (int r = 0; r < 4; ++r)
                        q_o[((size_t)(b * NH + h) * SEQ + s + r) * HD + d] =
                            f2bf((acc[mi][ni][r] + bias) * QSCL);
                } else if (which == 1) {
#pragma unroll
                    for (int r = 0; r < 4; ++r)
                        k_o[((size_t)(b * NH + h) * SEQ + s + r) * HD + d] =
                            f2bf(acc[mi][ni][r] + bias);
                } else {
                    ushort4v pk;
#pragma unroll
                    for (int r = 0; r < 4; ++r)
                        pk[r] = f2bf(acc[mi][ni][r] + bias);
                    *reinterpret_cast<ushort4v*>(
                        &vt_o[((size_t)(b * NH + h) * HD + d) * SEQ + s]) = pk;
                }
            }
        } else {
            const float bias = b0[n_g];
#pragma unroll
            for (int mi = 0; mi < 4; ++mi) {
                const int m_g = m0 + wr * 64 + mi * 16 + g * 4;
#pragma unroll
                for (int r = 0; r < 4; ++r)
                    c_out[(size_t)(m_g + r) * DIMSZ + n_g] = acc[mi][ni][r] + bias;
            }
        }
    }
}

// ---------------------------------------------------------------------------
// Flash tile, swapped QK^T: st[ni] = S^T[key=16ni+4g+r][q=c] via mfma(K, Q).
// Lane (c,g) owns q-row c: softmax = 15 in-lane ops + 2 shfl (max) + 2 (sum).
// P packed in-register (cvt_pk); PV B-frag keys follow the pack bijection
// sigma(kk,g,e) = 16*(2kk+(e>>2)) + 4g + (e&3)  -> two b64 V reads per frag.
// O rescale: fac of output row (4g+r) pulled from lane (4g+r) via bpermute.
// ---------------------------------------------------------------------------
__device__ __forceinline__ void attn_tile(
    const short8 (&qa)[2], f32x4 (&accO)[4], float &m_run, float &l_run,
    const unsigned short* Ks, const unsigned short* Vts,
    const int c, const int g, const int w, const bool masked)
{
    constexpr int KS = 72;
    f32x4 st[4];
#pragma unroll
    for (int ni = 0; ni < 4; ++ni) st[ni] = (f32x4){0.f, 0.f, 0.f, 0.f};

    __builtin_amdgcn_s_setprio(1);
#pragma unroll
    for (int kk = 0; kk < 2; ++kk)
#pragma unroll
        for (int ni = 0; ni < 4; ++ni) {
            const short8 kf = *reinterpret_cast<const short8*>(
                &Ks[(ni * 16 + c) * KS + kk * 32 + g * 8]);
            st[ni] = __builtin_amdgcn_mfma_f32_16x16x32_bf16(
                kf, qa[kk], st[ni], 0, 0, 0);        // S^T[key][q]
        }
    __builtin_amdgcn_s_setprio(0);

    if (masked) {                // keep key >= q (tile-relative: j0 == i0)
#pragma unroll
        for (int ni = 0; ni < 4; ++ni)
#pragma unroll
            for (int r = 0; r < 4; ++r)
                if (ni * 16 + g * 4 + r < w * 16 + c) st[ni][r] = -1e30f;
    }

    // ---- in-register online softmax for q-row c ----------------------------
    float mx = -1e30f;
#pragma unroll
    for (int ni = 0; ni < 4; ++ni)
        mx = fmaxf(mx, fmaxf(fmaxf(st[ni][0], st[ni][1]),
                             fmaxf(st[ni][2], st[ni][3])));
    mx = fmaxf(mx, __shfl_xor(mx, 16));
    mx = fmaxf(mx, __shfl_xor(mx, 32));
    const float newm = fmaxf(m_run, mx);
    const float fac = exp2f(m_run - newm);
    float rs = 0.f;
#pragma unroll
    for (int ni = 0; ni < 4; ++ni)
#pragma unroll
        for (int r = 0; r < 4; ++r) {
            const float p = exp2f(st[ni][r] - newm);
            st[ni][r] = p;
            rs += p;
        }
    rs += __shfl_xor(rs, 16);
    rs += __shfl_xor(rs, 32);
    m_run = newm;
    l_run = l_run * fac + rs;

    // ---- rescale O: row (4g+r)'s fac lives in lane (4g+r) ------------------
#pragma unroll
    for (int r = 0; r < 4; ++r) {
        const float fr = __int_as_float(__builtin_amdgcn_ds_bpermute(
            (g * 4 + r) * 4, __float_as_int(fac)));
#pragma unroll
        for (int ni = 0; ni < 4; ++ni) accO[ni][r] *= fr;
    }

    // ---- pack lane-local P row into A-fragments (no shuffles, no LDS) ------
    short8 pa[2];
#pragma unroll
    for (int kk = 0; kk < 2; ++kk) {
        union { unsigned int u[4]; short8 s; } pu;
        pu.u[0] = cvt_pk_bf16(st[2 * kk][0], st[2 * kk][1]);
        pu.u[1] = cvt_pk_bf16(st[2 * kk][2], st[2 * kk][3]);
        pu.u[2] = cvt_pk_bf16(st[2 * kk + 1][0], st[2 * kk + 1][1]);
        pu.u[3] = cvt_pk_bf16(st[2 * kk + 1][2], st[2 * kk + 1][3]);
        pa[kk] = pu.s;
    }

    // ---- O += P @ V (B-frag key order matches sigma) -----------------------
    __builtin_amdgcn_s_setprio(1);
#pragma unroll
    for (int kk = 0; kk < 2; ++kk)
#pragma unroll
        for (int ni = 0; ni < 4; ++ni) {
            union { short4v h[2]; short8 s; } vu;
            vu.h[0] = *reinterpret_cast<const short4v*>(
                &Vts[(ni * 16 + c) * KS + kk * 32 + g * 4]);
            vu.h[1] = *reinterpret_cast<const short4v*>(
                &Vts[(ni * 16 + c) * KS + kk * 32 + 16 + g * 4]);
            accO[ni] = __builtin_amdgcn_mfma_f32_16x16x32_bf16(
                pa[kk], vu.s, accO[ni], 0, 0, 0);
        }
    __builtin_amdgcn_s_setprio(0);
}

// ---------------------------------------------------------------------------
// Paired flash attention: block x handles qt1=x and qt2=31-x (33 tiles each).
// ---------------------------------------------------------------------------
__global__ __launch_bounds__(256, 2) void flash_mfma(
    const unsigned short* __restrict__ q, const unsigned short* __restrict__ k,
    const unsigned short* __restrict__ vt, unsigned short* __restrict__ o)
{
    constexpr int KS = 72;
    __shared__ unsigned short Ks[64 * KS];
    __shared__ unsigned short Vts[64 * KS];

    const int tid = threadIdx.x, lane = tid & 63, w = tid >> 6;
    const int c = lane & 15, g = lane >> 4;
    const int qt1 = blockIdx.x;          // 0..15
    const int qt2 = 31 - qt1;            // 31..16
    const int h = blockIdx.y, b = blockIdx.z;
    const int head = b * NH + h;
    const unsigned short* kh = k + (size_t)head * SEQ * HD;
    const unsigned short* vth = vt + (size_t)head * HD * SEQ;

    short8 qa1[2], qa2[2];
    {
        const size_t qb1 = ((size_t)head * SEQ + qt1 * 64 + w * 16 + c) * HD;
        qa1[0] = *reinterpret_cast<const short8*>(&q[qb1 + g * 8]);
        qa1[1] = *reinterpret_cast<const short8*>(&q[qb1 + 32 + g * 8]);
        const size_t qb2 = ((size_t)head * SEQ + qt2 * 64 + w * 16 + c) * HD;
        qa2[0] = *reinterpret_cast<const short8*>(&q[qb2 + g * 8]);
        qa2[1] = *reinterpret_cast<const short8*>(&q[qb2 + 32 + g * 8]);
    }

    f32x4 acc1[4], acc2[4];
    float m1 = -1e30f, l1 = 0.f, m2 = -1e30f, l2 = 0.f;
#pragma unroll
    for (int i = 0; i < 4; ++i) {
        acc1[i] = (f32x4){0.f, 0.f, 0.f, 0.f};
        acc2[i] = (f32x4){0.f, 0.f, 0.f, 0.f};
    }

    short8 kreg[2], vreg[2];
    {
        const int j0 = qt1 * 64;
#pragma unroll
        for (int rr = 0; rr < 2; ++rr) {
            const int chunk = rr * 256 + tid;
            const int row = chunk >> 3, d0 = (chunk & 7) * 8;
            kreg[rr] = *reinterpret_cast<const short8*>(&kh[(size_t)(j0 + row) * HD + d0]);
            vreg[rr] = *reinterpret_cast<const short8*>(&vth[(size_t)row * SEQ + j0 + d0]);
        }
    }

    for (int jt = qt1; jt < SEQ / 64; ++jt) {
        __syncthreads();                 // prior tile's LDS reads complete
#pragma unroll
        for (int rr = 0; rr < 2; ++rr) {
            const int chunk = rr * 256 + tid;
            const int row = chunk >> 3, d0 = (chunk & 7) * 8;
            *reinterpret_cast<short8*>(&Ks[row * KS + d0]) = kreg[rr];
            *reinterpret_cast<short8*>(&Vts[row * KS + d0]) = vreg[rr];
        }
        __syncthreads();
        if (jt + 1 < SEQ / 64) {         // prefetch next tile under compute
            const int j0 = (jt + 1) * 64;
#pragma unroll
            for (int rr = 0; rr < 2; ++rr) {
                const int chunk = rr * 256 + tid;
                const int row = chunk >> 3, d0 = (chunk & 7) * 8;
                kreg[rr] = *reinterpret_cast<const short8*>(&kh[(size_t)(j0 + row) * HD + d0]);
                vreg[rr] = *reinterpret_cast<const short8*>(&vth[(size_t)row * SEQ + j0 + d0]);
            }
        }

        attn_tile(qa1, acc1, m1, l1, Ks, Vts, c, g, w, jt == qt1);
        if (jt >= qt2)
            attn_tile(qa2, acc2, m2, l2, Ks, Vts, c, g, w, jt == qt2);
    }

    // ---- epilogue: o[B,S,D] bf16; 1/l of row (4g+r) via bpermute ------------
#pragma unroll
    for (int r = 0; r < 4; ++r) {
        const float l1r = __int_as_float(__builtin_amdgcn_ds_bpermute(
            (g * 4 + r) * 4, __float_as_int(l1)));
        const float l2r = __int_as_float(__builtin_amdgcn_ds_bpermute(
            (g * 4 + r) * 4, __float_as_int(l2)));
        const float inv1 = 1.0f / l1r, inv2 = 1.0f / l2r;
#pragma unroll
        for (int ni = 0; ni < 4; ++ni) {
            const int d = ni * 16 + c;
            const int r1 = qt1 * 64 + w * 16 + g * 4 + r;
            o[((size_t)b * SEQ + r1) * DIMSZ + h * HD + d] =
                f2bf(acc1[ni][r] * inv1);
            const int r2 = qt2 * 64 + w * 16 + g * 4 + r;
            o[((size_t)b * SEQ + r2) * DIMSZ + h * HD + d] =
                f2bf(acc2[ni][r] * inv2);
        }
    }
}

// ---------------------------------------------------------------------------
extern "C" void kernel_launch(void* const* d_in, const int* in_sizes, int n_in,
                              void* d_out, int out_size, void* d_ws, size_t ws_size,
                              hipStream_t stream)
{
    const float* x  = (const float*)d_in[0];
    const float* wq = (const float*)d_in[1];
    const float* bq = (const float*)d_in[2];
    const float* wk = (const float*)d_in[3];
    const float* bk = (const float*)d_in[4];
    const float* wv = (const float*)d_in[5];
    const float* bv = (const float*)d_in[6];
    const float* wo = (const float*)d_in[7];
    const float* bo = (const float*)d_in[8];
    float* out = (float*)d_out;

    const size_t M4 = (size_t)4 * 1024 * 1024;
    unsigned short* p = (unsigned short*)d_ws;
    unsigned short* x_bf  = p;           // [4096][1024]
    unsigned short* wt    = p + M4;      // [4][1024][1024]
    unsigned short* q_bf  = p + 2 * M4;  // [B,H,S,hd], pre-scaled by QSCL
    unsigned short* k_bf  = p + 3 * M4;  // [B,H,S,hd]
    unsigned short* vt_bf = p + 4 * M4;  // [B,H,hd,S]
    unsigned short* abf   = p + 5 * M4;  // [4096][1024]

    cvt_x<<<2048, 256, 0, stream>>>(x, x_bf);
    cvt_w<<<dim3(16, 16, 4), 256, 0, stream>>>(wq, wk, wv, wo, wt);

    mfma_gemm<0><<<dim3(24, 32), 256, 0, stream>>>(
        x_bf, wt, bq, bk, bv, q_bf, k_bf, vt_bf, nullptr);

    flash_mfma<<<dim3(16, 16, 2), 256, 0, stream>>>(q_bf, k_bf, vt_bf, abf);

    mfma_gemm<1><<<dim3(8, 32), 256, 0, stream>>>(
        abf, wt + (size_t)3 * 1024 * 1024, bo, nullptr, nullptr,
        nullptr, nullptr, nullptr, out);
}

// Round 11
// 200.269 us; speedup vs baseline: 6.0813x; 1.0566x over previous
//
#include <hip/hip_runtime.h>
#include <hip/hip_bf16.h>

// MHA: x[2,2048,1024] fp32 -> bf16 MFMA pipeline.
// R11: QKV GEMM epilogue restaged through LDS for coalesced q/k/v writes
//      (which-index is block-uniform); O-proj uses BM=64 tile -> 512 blocks
//      (2/CU, was 1/CU). Flash (swapped-QK^T in-register softmax) unchanged.

constexpr int NH    = 16;
constexpr int HD    = 64;
constexpr int BATCH = 2;
constexpr int SEQ   = 2048;
constexpr int DIMSZ = 1024;
constexpr float SCALE = 1.0f / 64.0f;
constexpr float QSCL = SCALE * 1.44269504088896f;   // fold log2(e): softmax in exp2 domain

typedef __attribute__((ext_vector_type(8))) short short8;
typedef __attribute__((ext_vector_type(4))) short short4v;
typedef __attribute__((ext_vector_type(4))) float f32x4;

__device__ inline unsigned short f2bf(float f) {
    __hip_bfloat16 h = __float2bfloat16(f);
    unsigned short u;
    __builtin_memcpy(&u, &h, 2);
    return u;
}

__device__ __forceinline__ unsigned int cvt_pk_bf16(float lo, float hi) {
    unsigned int r;
    asm("v_cvt_pk_bf16_f32 %0, %1, %2" : "=v"(r) : "v"(lo), "v"(hi));
    return r;
}

// async global->LDS, 16B per lane; LDS dest is wave-uniform base + lane*16.
__device__ __forceinline__ void gload_lds16(const void* g, void* l) {
    __builtin_amdgcn_global_load_lds(
        (const __attribute__((address_space(1))) unsigned int*)g,
        (__attribute__((address_space(3))) unsigned int*)l, 16, 0, 0);
}

// ---------------------------------------------------------------------------
// x fp32 -> bf16, 8 elems/thread.
// ---------------------------------------------------------------------------
__global__ __launch_bounds__(256) void cvt_x(const float* __restrict__ src,
                                             unsigned short* __restrict__ dst)
{
    const int i = blockIdx.x * 256 + threadIdx.x;
    const float4* s4 = reinterpret_cast<const float4*>(src);
    const float4 a = s4[(size_t)i * 2];
    const float4 b = s4[(size_t)i * 2 + 1];
    short8 o;
    o[0] = (short)f2bf(a.x); o[1] = (short)f2bf(a.y);
    o[2] = (short)f2bf(a.z); o[3] = (short)f2bf(a.w);
    o[4] = (short)f2bf(b.x); o[5] = (short)f2bf(b.y);
    o[6] = (short)f2bf(b.z); o[7] = (short)f2bf(b.w);
    *reinterpret_cast<short8*>(&dst[(size_t)i * 8]) = o;
}

// ---------------------------------------------------------------------------
// Weights: w[k][n] fp32 -> wt[which][n][k] bf16 (transposed). 64x64 LDS tiles.
// ---------------------------------------------------------------------------
__global__ __launch_bounds__(256) void cvt_w(const float* __restrict__ wq,
                                             const float* __restrict__ wk,
                                             const float* __restrict__ wv,
                                             const float* __restrict__ wo,
                                             unsigned short* __restrict__ wt)
{
    __shared__ float tile[64][65];
    const int t = threadIdx.x;
    const float* src = (blockIdx.z == 0) ? wq : (blockIdx.z == 1) ? wk
                     : (blockIdx.z == 2) ? wv : wo;
    const int n0 = blockIdx.x * 64, k0 = blockIdx.y * 64;

#pragma unroll
    for (int r = 0; r < 64; r += 16) {
        const int row = r + (t >> 4);
        const int c4 = (t & 15) * 4;
        const float4 v = *reinterpret_cast<const float4*>(
            &src[(size_t)(k0 + row) * DIMSZ + n0 + c4]);
        tile[row][c4 + 0] = v.x;
        tile[row][c4 + 1] = v.y;
        tile[row][c4 + 2] = v.z;
        tile[row][c4 + 3] = v.w;
    }
    __syncthreads();
#pragma unroll
    for (int rr = 0; rr < 2; ++rr) {
        const int n = rr * 32 + (t >> 3);
        const int kk0 = (t & 7) * 8;
        short8 pk;
#pragma unroll
        for (int e = 0; e < 8; ++e)
            pk[e] = (short)f2bf(tile[kk0 + e][n]);
        *reinterpret_cast<short8*>(
            &wt[((size_t)blockIdx.z * DIMSZ + n0 + n) * DIMSZ + k0 + kk0]) = pk;
    }
}

// ---------------------------------------------------------------------------
// MFMA GEMM, global_load_lds staging, double-buffered LDS, BMx128 tile, BK=64.
// 4 waves (2x2); wave tile (BM/2)x64; MI = BM/32 m-frags x 4 n-frags.
// EPI 0 (BM=128): QKV epilogue, LDS-restaged coalesced writes; which = nb0>>10
//   is block-uniform (q scaled by QSCL -> [B,H,S,hd]; k -> [B,H,S,hd];
//   v -> [B,H,hd,S]).
// EPI 1: fp32 C = acc + bias (row-major).
// ---------------------------------------------------------------------------
template <int EPI, int BM>
__global__ __launch_bounds__(256, 2) void mfma_gemm(
    const unsigned short* __restrict__ A, const unsigned short* __restrict__ Bt,
    const float* __restrict__ b0, const float* __restrict__ b1,
    const float* __restrict__ b2,
    unsigned short* __restrict__ q_o, unsigned short* __restrict__ k_o,
    unsigned short* __restrict__ vt_o, float* __restrict__ c_out)
{
    constexpr int MI = BM / 32;
    __shared__ __align__(16) unsigned short smem[2 * BM * 64 + 2 * 128 * 64];
    unsigned short* const A0 = smem;
    unsigned short* const A1 = smem + BM * 64;
    unsigned short* const B0 = smem + 2 * BM * 64;
    unsigned short* const B1 = smem + 2 * BM * 64 + 128 * 64;

    const int tid = threadIdx.x;
    const int lane = tid & 63;
    const int wv_ = tid >> 6;
    const int wr = wv_ >> 1, wc = wv_ & 1;
    const int c = lane & 15, g = lane >> 4;
    const int m0 = blockIdx.y * BM;
    const int nb0 = blockIdx.x * 128;
    const int wbase = (tid & 192) * 8;        // wave-uniform LDS u16 offset
    const int lrow = tid >> 3, ld0 = (tid & 7) * 8;

    f32x4 acc[MI][4];
#pragma unroll
    for (int i = 0; i < MI; ++i)
#pragma unroll
        for (int j = 0; j < 4; ++j)
            acc[i][j] = (f32x4){0.f, 0.f, 0.f, 0.f};

    auto issue = [&](unsigned short* dA, unsigned short* dB, int k0) {
#pragma unroll
        for (int it = 0; it < BM / 32; ++it) {
            const int row = it * 32 + lrow;
            gload_lds16(&A[(size_t)(m0 + row) * DIMSZ + k0 + ld0],
                        &dA[it * 2048 + wbase]);
        }
#pragma unroll
        for (int it = 0; it < 4; ++it) {
            const int row = it * 32 + lrow;
            gload_lds16(&Bt[(size_t)(nb0 + row) * DIMSZ + k0 + ld0],
                        &dB[it * 2048 + wbase]);
        }
    };

    auto compute = [&](const unsigned short* Ac, const unsigned short* Bc) {
#pragma unroll
        for (int kk = 0; kk < 2; ++kk) {
            short8 af[MI], bfr[4];
#pragma unroll
            for (int mi = 0; mi < MI; ++mi)
                af[mi] = *reinterpret_cast<const short8*>(
                    &Ac[(wr * (BM / 2) + mi * 16 + c) * 64 + kk * 32 + g * 8]);
#pragma unroll
            for (int ni = 0; ni < 4; ++ni)
                bfr[ni] = *reinterpret_cast<const short8*>(
                    &Bc[(wc * 64 + ni * 16 + c) * 64 + kk * 32 + g * 8]);
            __builtin_amdgcn_s_setprio(1);
#pragma unroll
            for (int mi = 0; mi < MI; ++mi)
#pragma unroll
                for (int ni = 0; ni < 4; ++ni)
                    acc[mi][ni] = __builtin_amdgcn_mfma_f32_16x16x32_bf16(
                        af[mi], bfr[ni], acc[mi][ni], 0, 0, 0);
            __builtin_amdgcn_s_setprio(0);
        }
    };

    issue(A0, B0, 0);
#pragma unroll 1
    for (int kt = 0; kt < DIMSZ / 64; kt += 2) {
        __syncthreads();                       // drains own vmcnt -> buf0 ready
        if (kt + 1 < DIMSZ / 64) issue(A1, B1, (kt + 1) * 64);
        compute(A0, B0);
        __syncthreads();                       // buf1 ready
        if (kt + 2 < DIMSZ / 64) issue(A0, B0, (kt + 2) * 64);
        compute(A1, B1);
    }

    // ---- epilogue -----------------------------------------------------------
    if (EPI == 0) {
        // which is uniform per block (128 | 1024)
        const int which = nb0 >> 10;
        const int nn0 = nb0 & 1023;
        const int h0 = nn0 >> 6;               // tile covers heads h0, h0+1
        const int b = m0 >> 11, s0 = m0 & 2047;
        const float* bias_p = which == 0 ? b0 : which == 1 ? b1 : b2;
        constexpr int LST = 136;               // row stride (u16), 16B-aligned
        unsigned short* L = smem;              // 128 x 136 u16 overlay (34 KB)

        __syncthreads();                       // all K-loop LDS reads done
        if (which == 2) {
            // ---- v: restage transposed L[n][s], emit [B,H,hd,S] rows -------
#pragma unroll
            for (int mi = 0; mi < MI; ++mi)
#pragma unroll
                for (int ni = 0; ni < 4; ++ni) {
                    const int n_l = wc * 64 + ni * 16 + c;
                    const float bias = bias_p[nn0 + n_l];
#pragma unroll
                    for (int r = 0; r < 4; ++r) {
                        const int s_l = wr * 64 + mi * 16 + g * 4 + r;
                        L[n_l * LST + s_l] = f2bf(acc[mi][ni][r] + bias);
                    }
                }
            __syncthreads();
#pragma unroll
            for (int p = 0; p < 8; ++p) {
                const int idx = p * 256 + tid;       // 0..2047
                const int drow = idx >> 4;           // 0..127 (= hh*64 + d)
                const int so = (idx & 15) * 8;
                const short8 vv = *reinterpret_cast<const short8*>(
                    &L[drow * LST + so]);
                const int hh = drow >> 6, d = drow & 63;
                *reinterpret_cast<short8*>(
                    &vt_o[((size_t)(b * NH + h0 + hh) * HD + d) * SEQ + s0 + so]) = vv;
            }
        } else {
            // ---- q/k: restage L[s][n], emit contiguous [S][hd] head blocks -
            unsigned short* dst = which == 0 ? q_o : k_o;
            const float scl = which == 0 ? QSCL : 1.0f;
#pragma unroll
            for (int mi = 0; mi < MI; ++mi)
#pragma unroll
                for (int ni = 0; ni < 4; ++ni) {
                    const int n_l = wc * 64 + ni * 16 + c;
                    const float bias = bias_p[nn0 + n_l];
#pragma unroll
                    for (int r = 0; r < 4; ++r) {
                        const int s_l = wr * 64 + mi * 16 + g * 4 + r;
                        L[s_l * LST + n_l] = f2bf((acc[mi][ni][r] + bias) * scl);
                    }
                }
            __syncthreads();
#pragma unroll
            for (int p = 0; p < 8; ++p) {
                const int idx = p * 256 + tid;       // 0..2047
                const int hh = idx >> 10;            // passes 0-3: h0, 4-7: h0+1
                const int eo = (idx & 1023) * 8;     // u16 offset in 16KB block
                const int s_l = eo >> 6, d0 = eo & 63;
                const short8 vv = *reinterpret_cast<const short8*>(
                    &L[s_l * LST + hh * 64 + d0]);
                *reinterpret_cast<short8*>(
                    &dst[((size_t)(b * NH + h0 + hh) * SEQ + s0) * HD + eo]) = vv;
            }
        }
    } else {
#pragma unroll
        for (int ni = 0; ni < 4; ++ni) {
            const int n_g = nb0 + wc * 64 + ni * 16 + c;
            const float bias = b0[n_g];
#pragma unroll
            for (int mi = 0; mi < MI; ++mi) {
                const int m_g = m0 + wr * (BM / 2) + mi * 16 + g * 4;
#pragma unroll
                for (int r = 0; r < 4; ++r)
                    c_out[(size_t)(m_g + r) * DIMSZ + n_g] = acc[mi][ni][r] + bias;
            }
        }
    }
}

// ---------------------------------------------------------------------------
// Flash tile, swapped QK^T: st[ni] = S^T[key=16ni+4g+r][q=c] via mfma(K, Q).
// Lane (c,g) owns q-row c; softmax fully in-register (4 shuffles/tile).
// P packed via v_cvt_pk_bf16_f32; PV B-frag key order matches pack bijection.
// ---------------------------------------------------------------------------
__device__ __forceinline__ void attn_tile(
    const short8 (&qa)[2], f32x4 (&accO)[4], float &m_run, float &l_run,
    const unsigned short* Ks, const unsigned short* Vts,
    const int c, const int g, const int w, const bool masked)
{
    constexpr int KS = 72;
    f32x4 st[4];
#pragma unroll
    for (int ni = 0; ni < 4; ++ni) st[ni] = (f32x4){0.f, 0.f, 0.f, 0.f};

    __builtin_amdgcn_s_setprio(1);
#pragma unroll
    for (int kk = 0; kk < 2; ++kk)
#pragma unroll
        for (int ni = 0; ni < 4; ++ni) {
            const short8 kf = *reinterpret_cast<const short8*>(
                &Ks[(ni * 16 + c) * KS + kk * 32 + g * 8]);
            st[ni] = __builtin_amdgcn_mfma_f32_16x16x32_bf16(
                kf, qa[kk], st[ni], 0, 0, 0);        // S^T[key][q]
        }
    __builtin_amdgcn_s_setprio(0);

    if (masked) {                // keep key >= q (tile-relative: j0 == i0)
#pragma unroll
        for (int ni = 0; ni < 4; ++ni)
#pragma unroll
            for (int r = 0; r < 4; ++r)
                if (ni * 16 + g * 4 + r < w * 16 + c) st[ni][r] = -1e30f;
    }

    // ---- in-register online softmax for q-row c ----------------------------
    float mx = -1e30f;
#pragma unroll
    for (int ni = 0; ni < 4; ++ni)
        mx = fmaxf(mx, fmaxf(fmaxf(st[ni][0], st[ni][1]),
                             fmaxf(st[ni][2], st[ni][3])));
    mx = fmaxf(mx, __shfl_xor(mx, 16));
    mx = fmaxf(mx, __shfl_xor(mx, 32));
    const float newm = fmaxf(m_run, mx);
    const float fac = exp2f(m_run - newm);
    float rs = 0.f;
#pragma unroll
    for (int ni = 0; ni < 4; ++ni)
#pragma unroll
        for (int r = 0; r < 4; ++r) {
            const float p = exp2f(st[ni][r] - newm);
            st[ni][r] = p;
            rs += p;
        }
    rs += __shfl_xor(rs, 16);
    rs += __shfl_xor(rs, 32);
    m_run = newm;
    l_run = l_run * fac + rs;

    // ---- rescale O: row (4g+r)'s fac lives in lane (4g+r) ------------------
#pragma unroll
    for (int r = 0; r < 4; ++r) {
        const float fr = __int_as_float(__builtin_amdgcn_ds_bpermute(
            (g * 4 + r) * 4, __float_as_int(fac)));
#pragma unroll
        for (int ni = 0; ni < 4; ++ni) accO[ni][r] *= fr;
    }

    // ---- pack lane-local P row into A-fragments (no shuffles, no LDS) ------
    short8 pa[2];
#pragma unroll
    for (int kk = 0; kk < 2; ++kk) {
        union { unsigned int u[4]; short8 s; } pu;
        pu.u[0] = cvt_pk_bf16(st[2 * kk][0], st[2 * kk][1]);
        pu.u[1] = cvt_pk_bf16(st[2 * kk][2], st[2 * kk][3]);
        pu.u[2] = cvt_pk_bf16(st[2 * kk + 1][0], st[2 * kk + 1][1]);
        pu.u[3] = cvt_pk_bf16(st[2 * kk + 1][2], st[2 * kk + 1][3]);
        pa[kk] = pu.s;
    }

    // ---- O += P @ V (B-frag key order matches sigma) -----------------------
    __builtin_amdgcn_s_setprio(1);
#pragma unroll
    for (int kk = 0; kk < 2; ++kk)
#pragma unroll
        for (int ni = 0; ni < 4; ++ni) {
            union { short4v h[2]; short8 s; } vu;
            vu.h[0] = *reinterpret_cast<const short4v*>(
                &Vts[(ni * 16 + c) * KS + kk * 32 + g * 4]);
            vu.h[1] = *reinterpret_cast<const short4v*>(
                &Vts[(ni * 16 + c) * KS + kk * 32 + 16 + g * 4]);
            accO[ni] = __builtin_amdgcn_mfma_f32_16x16x32_bf16(
                pa[kk], vu.s, accO[ni], 0, 0, 0);
        }
    __builtin_amdgcn_s_setprio(0);
}

// ---------------------------------------------------------------------------
// Paired flash attention: block x handles qt1=x and qt2=31-x (33 tiles each).
// ---------------------------------------------------------------------------
__global__ __launch_bounds__(256, 2) void flash_mfma(
    const unsigned short* __restrict__ q, const unsigned short* __restrict__ k,
    const unsigned short* __restrict__ vt, unsigned short* __restrict__ o)
{
    constexpr int KS = 72;
    __shared__ unsigned short Ks[64 * KS];
    __shared__ unsigned short Vts[64 * KS];

    const int tid = threadIdx.x, lane = tid & 63, w = tid >> 6;
    const int c = lane & 15, g = lane >> 4;
    const int qt1 = blockIdx.x;          // 0..15
    const int qt2 = 31 - qt1;            // 31..16
    const int h = blockIdx.y, b = blockIdx.z;
    const int head = b * NH + h;
    const unsigned short* kh = k + (size_t)head * SEQ * HD;
    const unsigned short* vth = vt + (size_t)head * HD * SEQ;

    short8 qa1[2], qa2[2];
    {
        const size_t qb1 = ((size_t)head * SEQ + qt1 * 64 + w * 16 + c) * HD;
        qa1[0] = *reinterpret_cast<const short8*>(&q[qb1 + g * 8]);
        qa1[1] = *reinterpret_cast<const short8*>(&q[qb1 + 32 + g * 8]);
        const size_t qb2 = ((size_t)head * SEQ + qt2 * 64 + w * 16 + c) * HD;
        qa2[0] = *reinterpret_cast<const short8*>(&q[qb2 + g * 8]);
        qa2[1] = *reinterpret_cast<const short8*>(&q[qb2 + 32 + g * 8]);
    }

    f32x4 acc1[4], acc2[4];
    float m1 = -1e30f, l1 = 0.f, m2 = -1e30f, l2 = 0.f;
#pragma unroll
    for (int i = 0; i < 4; ++i) {
        acc1[i] = (f32x4){0.f, 0.f, 0.f, 0.f};
        acc2[i] = (f32x4){0.f, 0.f, 0.f, 0.f};
    }

    short8 kreg[2], vreg[2];
    {
        const int j0 = qt1 * 64;
#pragma unroll
        for (int rr = 0; rr < 2; ++rr) {
            const int chunk = rr * 256 + tid;
            const int row = chunk >> 3, d0 = (chunk & 7) * 8;
            kreg[rr] = *reinterpret_cast<const short8*>(&kh[(size_t)(j0 + row) * HD + d0]);
            vreg[rr] = *reinterpret_cast<const short8*>(&vth[(size_t)row * SEQ + j0 + d0]);
        }
    }

    for (int jt = qt1; jt < SEQ / 64; ++jt) {
        __syncthreads();                 // prior tile's LDS reads complete
#pragma unroll
        for (int rr = 0; rr < 2; ++rr) {
            const int chunk = rr * 256 + tid;
            const int row = chunk >> 3, d0 = (chunk & 7) * 8;
            *reinterpret_cast<short8*>(&Ks[row * KS + d0]) = kreg[rr];
            *reinterpret_cast<short8*>(&Vts[row * KS + d0]) = vreg[rr];
        }
        __syncthreads();
        if (jt + 1 < SEQ / 64) {         // prefetch next tile under compute
            const int j0 = (jt + 1) * 64;
#pragma unroll
            for (int rr = 0; rr < 2; ++rr) {
                const int chunk = rr * 256 + tid;
                const int row = chunk >> 3, d0 = (chunk & 7) * 8;
                kreg[rr] = *reinterpret_cast<const short8*>(&kh[(size_t)(j0 + row) * HD + d0]);
                vreg[rr] = *reinterpret_cast<const short8*>(&vth[(size_t)row * SEQ + j0 + d0]);
            }
        }

        attn_tile(qa1, acc1, m1, l1, Ks, Vts, c, g, w, jt == qt1);
        if (jt >= qt2)
            attn_tile(qa2, acc2, m2, l2, Ks, Vts, c, g, w, jt == qt2);
    }

    // ---- epilogue: o[B,S,D] bf16; 1/l of row (4g+r) via bpermute ------------
#pragma unroll
    for (int r = 0; r < 4; ++r) {
        const float l1r = __int_as_float(__builtin_amdgcn_ds_bpermute(
            (g * 4 + r) * 4, __float_as_int(l1)));
        const float l2r = __int_as_float(__builtin_amdgcn_ds_bpermute(
            (g * 4 + r) * 4, __float_as_int(l2)));
        const float inv1 = 1.0f / l1r, inv2 = 1.0f / l2r;
#pragma unroll
        for (int ni = 0; ni < 4; ++ni) {
            const int d = ni * 16 + c;
            const int r1 = qt1 * 64 + w * 16 + g * 4 + r;
            o[((size_t)b * SEQ + r1) * DIMSZ + h * HD + d] =
                f2bf(acc1[ni][r] * inv1);
            const int r2 = qt2 * 64 + w * 16 + g * 4 + r;
            o[((size_t)b * SEQ + r2) * DIMSZ + h * HD + d] =
                f2bf(acc2[ni][r] * inv2);
        }
    }
}

// ---------------------------------------------------------------------------
extern "C" void kernel_launch(void* const* d_in, const int* in_sizes, int n_in,
                              void* d_out, int out_size, void* d_ws, size_t ws_size,
                              hipStream_t stream)
{
    const float* x  = (const float*)d_in[0];
    const float* wq = (const float*)d_in[1];
    const float* bq = (const float*)d_in[2];
    const float* wk = (const float*)d_in[3];
    const float* bk = (const float*)d_in[4];
    const float* wv = (const float*)d_in[5];
    const float* bv = (const float*)d_in[6];
    const float* wo = (const float*)d_in[7];
    const float* bo = (const float*)d_in[8];
    float* out = (float*)d_out;

    const size_t M4 = (size_t)4 * 1024 * 1024;
    unsigned short* p = (unsigned short*)d_ws;
    unsigned short* x_bf  = p;           // [4096][1024]
    unsigned short* wt    = p + M4;      // [4][1024][1024]
    unsigned short* q_bf  = p + 2 * M4;  // [B,H,S,hd], pre-scaled by QSCL
    unsigned short* k_bf  = p + 3 * M4;  // [B,H,S,hd]
    unsigned short* vt_bf = p + 4 * M4;  // [B,H,hd,S]
    unsigned short* abf   = p + 5 * M4;  // [4096][1024]

    cvt_x<<<2048, 256, 0, stream>>>(x, x_bf);
    cvt_w<<<dim3(16, 16, 4), 256, 0, stream>>>(wq, wk, wv, wo, wt);

    mfma_gemm<0, 128><<<dim3(24, 32), 256, 0, stream>>>(
        x_bf, wt, bq, bk, bv, q_bf, k_bf, vt_bf, nullptr);

    flash_mfma<<<dim3(16, 16, 2), 256, 0, stream>>>(q_bf, k_bf, vt_bf, abf);

    mfma_gemm<1, 64><<<dim3(8, 64), 256, 0, stream>>>(
        abf, wt + (size_t)3 * 1024 * 1024, bo, nullptr, nullptr,
        nullptr, nullptr, nullptr, out);
}